// Round 1
// baseline (436.318 us; speedup 1.0000x reference)
//
#include <hip/hip_runtime.h>

// Cumulative average along last axis: y[..., t] = cumsum(x)[..., t] / (t+1)
// x: fp32, shape (8, 512, 16384) -> 4096 independent rows of T=16384.
// Memory-bound scan: one block per row, float4 coalesced loads,
// wave64 shfl scan + LDS wave-aggregate combine + register carry.

#define ROW_T   16384
#define THREADS 256
#define VEC     4
#define TILE    (THREADS * VEC)   // 1024 elements per tile
#define NTILES  (ROW_T / TILE)    // 16 tiles per row
#define NWAVES  (THREADS / 64)    // 4 waves

__global__ __launch_bounds__(THREADS)
void cumavg_kernel(const float* __restrict__ x, float* __restrict__ y) {
    const int  row  = blockIdx.x;
    const long base = (long)row * ROW_T;
    const int  tid  = threadIdx.x;
    const int  lane = tid & 63;
    const int  wave = tid >> 6;

    __shared__ float wsum[NWAVES];

    float carry = 0.0f;

    #pragma unroll 1
    for (int t = 0; t < NTILES; ++t) {
        const int off = t * TILE + tid * VEC;   // position within the row

        // Coalesced 16B/lane load
        float4 v = *reinterpret_cast<const float4*>(x + base + off);

        // Thread-local sum of its 4 contiguous elements
        float ts  = v.x + v.y + v.z + v.w;

        // Wave-64 inclusive scan of per-thread sums
        float inc = ts;
        #pragma unroll
        for (int d = 1; d < 64; d <<= 1) {
            float n = __shfl_up(inc, d, 64);
            if (lane >= d) inc += n;
        }

        // Publish wave totals
        if (lane == 63) wsum[wave] = inc;
        __syncthreads();

        // Every thread combines wave aggregates (only 4 -> cheap, broadcast reads)
        float woff = 0.0f, total = 0.0f;
        #pragma unroll
        for (int w = 0; w < NWAVES; ++w) {
            float s = wsum[w];
            if (w < wave) woff += s;
            total += s;
        }

        // Exclusive prefix for this thread's first element
        float ex = carry + woff + (inc - ts);

        // Per-element inclusive sums, then divide by (global index + 1)
        float s0 = ex + v.x;
        float s1 = s0 + v.y;
        float s2 = s1 + v.z;
        float s3 = s2 + v.w;

        float4 o;
        o.x = s0 / (float)(off + 1);
        o.y = s1 / (float)(off + 2);
        o.z = s2 / (float)(off + 3);
        o.w = s3 / (float)(off + 4);

        *reinterpret_cast<float4*>(y + base + off) = o;

        carry += total;
        __syncthreads();   // protect wsum before next tile overwrites it
    }
}

extern "C" void kernel_launch(void* const* d_in, const int* in_sizes, int n_in,
                              void* d_out, int out_size, void* d_ws, size_t ws_size,
                              hipStream_t stream) {
    const float* x = (const float*)d_in[0];
    float*       y = (float*)d_out;
    const int rows = in_sizes[0] / ROW_T;   // 8*512 = 4096
    hipLaunchKernelGGL(cumavg_kernel, dim3(rows), dim3(THREADS), 0, stream, x, y);
}